// Round 1
// baseline (523.966 us; speedup 1.0000x reference)
//
#include <hip/hip_runtime.h>
#include <cstdint>

typedef __attribute__((ext_vector_type(8))) short s8v;   // 8 x bf16 (as i16)
typedef __attribute__((ext_vector_type(4))) float f4v;   // MFMA accumulator

__device__ __forceinline__ unsigned short bf16_rne(float f) {
    unsigned u = __float_as_uint(f);
    u += 0x7FFFu + ((u >> 16) & 1u);
    return (unsigned short)(u >> 16);
}
__device__ __forceinline__ float bf16f(unsigned short h) {
    return __uint_as_float(((unsigned)h) << 16);
}
// RNE pair-split (used in build_B where VALU is not critical)
__device__ __forceinline__ void cvt2(float a, float b, unsigned& hiw, unsigned& low) {
    unsigned ua = __float_as_uint(a), ub = __float_as_uint(b);
    unsigned ha = ua + 0x7FFFu + ((ua >> 16) & 1u);
    unsigned hb = ub + 0x7FFFu + ((ub >> 16) & 1u);
    hiw = (ha >> 16) | (hb & 0xFFFF0000u);
    float ra = a - __uint_as_float(ha & 0xFFFF0000u);
    float rb = b - __uint_as_float(hb & 0xFFFF0000u);
    unsigned la = __float_as_uint(ra), lb = __float_as_uint(rb);
    la += 0x7FFFu + ((la >> 16) & 1u);
    lb += 0x7FFFu + ((lb >> 16) & 1u);
    low = (la >> 16) | (lb & 0xFFFF0000u);
}
// cheap truncation pair-split (conv inner loop): err <= 2^-16 |v|, ~10 VALU/pair
__device__ __forceinline__ void cvt2t(float a, float b, unsigned& hiw, unsigned& low) {
    unsigned ua = __float_as_uint(a), ub = __float_as_uint(b);
    hiw = (ua >> 16) | (ub & 0xFFFF0000u);
    float ra = a - __uint_as_float(ua & 0xFFFF0000u);
    float rb = b - __uint_as_float(ub & 0xFFFF0000u);
    unsigned la = __float_as_uint(ra), lb = __float_as_uint(rb);
    low = (la >> 16) | (lb & 0xFFFF0000u);
}

// ---------------- transpose x [c][784] -> xt [p][c] fp32 (coalesced both sides) ----------
__global__ __launch_bounds__(256) void transpose_x(const float* __restrict__ x,
                                                   float* __restrict__ xt) {
    __shared__ float t[64][65];
    int c0 = blockIdx.x * 64, p0 = blockIdx.y * 64;
    int l = threadIdx.x & 63, g = threadIdx.x >> 6;
#pragma unroll
    for (int j = 0; j < 16; ++j) {
        int cc = j * 4 + g;
        int p = p0 + l;
        t[cc][l] = (p < 784) ? x[(size_t)(c0 + cc) * 784 + p] : 0.f;
    }
    __syncthreads();
#pragma unroll
    for (int j = 0; j < 16; ++j) {
        int pp = j * 4 + g;
        int p = p0 + pp;
        if (p < 784) xt[(size_t)p * 2048 + c0 + l] = t[l][pp];
    }
}

// ---------------- build im2col B: xt [p][c] fp32 -> Bhi/Blo [p][k=c*9+r] bf16 ------------
__global__ __launch_bounds__(256) void build_B(const float* __restrict__ xt,
                                               unsigned* __restrict__ Bhi,
                                               unsigned* __restrict__ Blo) {
    int p = blockIdx.x;
    int h = p / 28, w = p % 28;
#pragma unroll
    for (int it = 0; it < 4; ++it) {
        int cp = it * 256 + threadIdx.x;   // c-pair index 0..1023, c0 = 2*cp
        float va[18];
#pragma unroll
        for (int r = 0; r < 9; ++r) {
            int h2 = h + r / 3 - 1, w2 = w + r % 3 - 1;
            bool ok = (h2 >= 0) & (h2 < 28) & (w2 >= 0) & (w2 < 28);
            float2 v = ok ? ((const float2*)(xt + (size_t)(h2 * 28 + w2) * 2048))[cp]
                          : float2{0.f, 0.f};
            va[r] = v.x;
            va[9 + r] = v.y;
        }
        size_t base = (size_t)p * 9216 + (size_t)cp * 9;  // dword index
#pragma unroll
        for (int d = 0; d < 9; ++d) {
            unsigned hw, lw;
            cvt2(va[2 * d], va[2 * d + 1], hw, lw);
            Bhi[base + d] = hw;
            Blo[base + d] = lw;
        }
    }
}

// ---------------- conv implicit GEMM over k=c*9+r; z=16 K-split; trunc split -------------
// Pipelined schedule (T3-minimum + T5): full LDS double-buffer (A and B), ONE barrier per
// K-step. Step t issues B-DMA(t+1) + writes A(t+1) into buf^1, then reads+MFMAs from buf.
// The vmcnt(0) drain at the barrier now lands AFTER the full MFMA phase instead of right
// after issue, so DMA latency is hidden under compute.
// LDS: A dbuf 2x16384 (hi 8K + lo 8K) at 0, B dbuf 2x14336 (hi 7168 + lo 7168) at 32768.
#define KCH 1152          // 16 * 1152 = 18432
#define NSTEP 36          // KCH / 32
#define LDS_BYTES 61440   // 2 blocks/CU (160K/60K) -> 8 waves/CU

__global__ __launch_bounds__(256, 2) void conv_gemm(const float* __restrict__ cw,
                                                    const char* __restrict__ wsb,
                                                    uint32_t offBhi, uint32_t offBlo,
                                                    float* __restrict__ part) {
    __shared__ char smem[LDS_BYTES];
    int tid = threadIdx.x;
    int lane = tid & 63, wave = tid >> 6;
    int bm0 = blockIdx.x * 128, bn0 = blockIdx.y * 112, z = blockIdx.z;

    // B staging: 14 real glds descriptors (7 hi + 7 lo tiles) + 2 benign dups.
    uint32_t doff[4], dldsB[4];   // dldsB is the offset WITHIN one B buffer (0..14335)
#pragma unroll
    for (int j = 0; j < 4; ++j) {
        int i = j * 4 + wave;           // 0..15
        if (i >= 14) i -= 2;            // dup (same src+dst: benign)
        bool hiP = i < 7;
        int jj = hiP ? i : i - 7;
        int prow = jj * 16 + (lane >> 2);
        int pos = lane & 3;
        int gblk = pos ^ ((prow >> 1) & 3);            // XOR swizzle @16B blocks
        uint32_t elem = (uint32_t)(bn0 + prow) * 18432 + (uint32_t)z * KCH + gblk * 8;
        doff[j] = (hiP ? offBhi : offBlo) + elem * 2;
        dldsB[j] = (hiP ? 0u : 7168u) + (uint32_t)jj * 1024;
    }

    int m = lane & 15, qd = lane >> 4;
    int sw = (m >> 1) & 3;
    uint32_t apos = (uint32_t)(wave * 32 + m) * 64 + (uint32_t)((qd ^ sw) * 16);
    uint32_t bpos = (uint32_t)m * 64 + (uint32_t)((qd ^ sw) * 16);
    int arow = tid >> 1, ahalf = tid & 1;              // 2 threads per A row
    int swt = (arow >> 1) & 3;                         // writer-row swizzle

    f4v acc[2][7];
#pragma unroll
    for (int a = 0; a < 2; ++a)
#pragma unroll
        for (int b = 0; b < 7; ++b) acc[a][b] = f4v{0.f, 0.f, 0.f, 0.f};

    // A: thread owns half-row (16 fp32/step) of conv_w row bm0+arow.
    const float4* ap = (const float4*)(cw + (size_t)(bm0 + arow) * 18432 + (size_t)z * KCH
                                       + (size_t)ahalf * 16);
    float4 ar[4];
#pragma unroll
    for (int j = 0; j < 4; ++j) ar[j] = ap[j];         // A(0)

    // A split+write helper: smA points at one A buffer (hi at +0, lo at +8192)
    auto writeA = [&](char* smA) {
        unsigned hw[8], lw[8];
#pragma unroll
        for (int j = 0; j < 4; ++j) {
            cvt2t(ar[j].x, ar[j].y, hw[2 * j], lw[2 * j]);
            cvt2t(ar[j].z, ar[j].w, hw[2 * j + 1], lw[2 * j + 1]);
        }
#pragma unroll
        for (int b = 0; b < 2; ++b) {
            uint32_t col = (uint32_t)(((2 * ahalf + b) ^ swt) * 16);
            *(uint4*)(smA + arow * 64 + col) =
                uint4{hw[4 * b], hw[4 * b + 1], hw[4 * b + 2], hw[4 * b + 3]};
            *(uint4*)(smA + 8192 + arow * 64 + col) =
                uint4{lw[4 * b], lw[4 * b + 1], lw[4 * b + 2], lw[4 * b + 3]};
        }
    };

    // ---- prologue: stage step 0 into buf0, prefetch A(1) into regs ----
#pragma unroll
    for (int j = 0; j < 4; ++j) {
        __builtin_amdgcn_global_load_lds(
            (const __attribute__((address_space(1))) void*)(wsb + doff[j]),
            (__attribute__((address_space(3))) void*)(smem + 32768 + dldsB[j]), 16, 0, 0);
        doff[j] += 64;  // 32 k * 2B
    }
    writeA(smem);                                      // A(0) -> buf0
    ap += 8;
#pragma unroll
    for (int j = 0; j < 4; ++j) ar[j] = ap[j];         // A(1)
    __syncthreads();

    // ---- main loop: one barrier per step ----
#pragma unroll 2
    for (int step = 0; step < NSTEP; ++step) {
        int buf = step & 1, nbuf = buf ^ 1;
        char* smA = smem + buf * 16384;
        char* smB = smem + 32768 + buf * 14336;

        if (step < NSTEP - 1) {
            // issue B-DMA(step+1) into the other buffer — drains only at end-of-step
            char* smBn = smem + 32768 + nbuf * 14336;
#pragma unroll
            for (int j = 0; j < 4; ++j) {
                __builtin_amdgcn_global_load_lds(
                    (const __attribute__((address_space(1))) void*)(wsb + doff[j]),
                    (__attribute__((address_space(3))) void*)(smBn + dldsB[j]), 16, 0, 0);
                doff[j] += 64;
            }
            // write A(step+1) into the other buffer; prefetch A(step+2) into regs
            writeA(smem + nbuf * 16384);
            if (step < NSTEP - 2) {
                ap += 8;
#pragma unroll
                for (int j = 0; j < 4; ++j) ar[j] = ap[j];
            }
        }

        s8v ah[2], al[2];
#pragma unroll
        for (int mt = 0; mt < 2; ++mt) {
            ah[mt] = *(const s8v*)(smA + apos + mt * 1024);
            al[mt] = *(const s8v*)(smA + 8192 + apos + mt * 1024);
        }
        __builtin_amdgcn_s_setprio(1);
#pragma unroll
        for (int nt = 0; nt < 7; ++nt) {
            s8v bh = *(const s8v*)(smB + bpos + nt * 1024);
            s8v bl = *(const s8v*)(smB + 7168 + bpos + nt * 1024);
#pragma unroll
            for (int mt = 0; mt < 2; ++mt) {
                acc[mt][nt] = __builtin_amdgcn_mfma_f32_16x16x32_bf16(ah[mt], bh, acc[mt][nt], 0, 0, 0);
                acc[mt][nt] = __builtin_amdgcn_mfma_f32_16x16x32_bf16(ah[mt], bl, acc[mt][nt], 0, 0, 0);
                acc[mt][nt] = __builtin_amdgcn_mfma_f32_16x16x32_bf16(al[mt], bh, acc[mt][nt], 0, 0, 0);
            }
        }
        __builtin_amdgcn_s_setprio(0);
        __syncthreads();   // drains this step's DMA (vmcnt) + A writes (lgkm), flips buffers
    }

    // epilogue: C row(o) = qd*4+reg, col(p) = m; one 16B store per tile
    float* pz = part + (size_t)z * 1605632;  // 784*2048
#pragma unroll
    for (int mt = 0; mt < 2; ++mt) {
        int o = bm0 + wave * 32 + mt * 16 + qd * 4;
#pragma unroll
        for (int nt = 0; nt < 7; ++nt) {
            int p = bn0 + nt * 16 + m;
            *(float4*)(pz + (size_t)p * 2048 + o) =
                float4{acc[mt][nt].x, acc[mt][nt].y, acc[mt][nt].z, acc[mt][nt].w};
        }
    }
}

// ---------------- heads: block per pixel; 16-partial reduce, 45 dots, sigmoid, scatter ---
__constant__ int HMIN_d[9] = {3, 2, 1, 6, 4, 3, 11, 8, 6};
__constant__ int WMIN_d[9] = {1, 2, 3, 3, 4, 6, 6, 8, 11};

__global__ __launch_bounds__(256) void heads(const float* __restrict__ part,
                                             const float* __restrict__ conv_b,
                                             const float* __restrict__ reg_w,
                                             const float* __restrict__ reg_b,
                                             const float* __restrict__ cls_w,
                                             const float* __restrict__ cls_b,
                                             float* __restrict__ out) {
    int tid = threadIdx.x;
    int lane = tid & 63, wave = tid >> 6;
    int p = blockIdx.x;                 // source pixel p'
    int ci = tid * 2;                   // float4-pair index: channels [tid*8, tid*8+8)

    float4 h0 = ((const float4*)conv_b)[ci];
    float4 h1 = ((const float4*)conv_b)[ci + 1];
#pragma unroll
    for (int z = 0; z < 16; ++z) {
        const float4* pz = (const float4*)(part + (size_t)z * 1605632 + (size_t)p * 2048);
        float4 a = pz[ci], b = pz[ci + 1];
        h0.x += a.x; h0.y += a.y; h0.z += a.z; h0.w += a.w;
        h1.x += b.x; h1.y += b.y; h1.z += b.z; h1.w += b.w;
    }
    h0.x = fmaxf(h0.x, 0.f); h0.y = fmaxf(h0.y, 0.f);
    h0.z = fmaxf(h0.z, 0.f); h0.w = fmaxf(h0.w, 0.f);
    h1.x = fmaxf(h1.x, 0.f); h1.y = fmaxf(h1.y, 0.f);
    h1.z = fmaxf(h1.z, 0.f); h1.w = fmaxf(h1.w, 0.f);

    float s[45];
#pragma unroll
    for (int o = 0; o < 36; ++o) {
        float4 wa = ((const float4*)(reg_w + (size_t)o * 2048))[ci];
        float4 wb = ((const float4*)(reg_w + (size_t)o * 2048))[ci + 1];
        s[o] = h0.x * wa.x + h0.y * wa.y + h0.z * wa.z + h0.w * wa.w +
               h1.x * wb.x + h1.y * wb.y + h1.z * wb.z + h1.w * wb.w;
    }
#pragma unroll
    for (int a = 0; a < 9; ++a) {
        float4 wa = ((const float4*)(cls_w + (size_t)a * 2048))[ci];
        float4 wb = ((const float4*)(cls_w + (size_t)a * 2048))[ci + 1];
        s[36 + a] = h0.x * wa.x + h0.y * wa.y + h0.z * wa.z + h0.w * wa.w +
                    h1.x * wb.x + h1.y * wb.y + h1.z * wb.z + h1.w * wb.w;
    }

    __shared__ float wsum[4][45];
    __shared__ float fin[45];
#pragma unroll
    for (int o = 0; o < 45; ++o) {
        float v = s[o];
#pragma unroll
        for (int d = 1; d < 64; d <<= 1) v += __shfl_xor(v, d, 64);
        if (lane == 0) wsum[wave][o] = v;
    }
    __syncthreads();
    if (tid < 45) fin[tid] = wsum[0][tid] + wsum[1][tid] + wsum[2][tid] + wsum[3][tid];
    __syncthreads();

    // Reference view-chain: valid set over n = pix*9 + a (geometry); data at row n from
    // channel a' = n//784, pixel p' = n%784. This block owns p'; n = a'*784 + p'.
    if (tid < 9) {
        int ap = tid;
        int n = ap * 784 + p;
        int pix = n / 9, a2 = n % 9;
        int hh = pix / 28, ww = pix % 28;
        if (hh >= HMIN_d[a2] && ww >= WMIN_d[a2]) {
            int row = 0;
#pragma unroll
            for (int a3 = 0; a3 < 9; ++a3) {
                int hm = HMIN_d[a3], wm = WMIN_d[a3];
                int full = hh - hm; if (full < 0) full = 0;
                row += full * (28 - wm);
                if (hh >= hm) { int prt = ww - wm; if (prt < 0) prt = 0; row += prt; }
                if (a3 < a2 && hh >= hm && ww >= wm) row += 1;
            }
            float cl = fin[36 + ap] + cls_b[ap];
            float keep = (1.f / (1.f + expf(-cl)) > 0.9f) ? 1.f : 0.f;
#pragma unroll
            for (int q = 0; q < 4; ++q) {
                float rl = fin[q * 9 + ap] + reg_b[q * 9 + ap];
                out[row * 4 + q] = keep / (1.f + expf(-rl));
            }
        }
    }
}

extern "C" void kernel_launch(void* const* d_in, const int* in_sizes, int n_in,
                              void* d_out, int out_size, void* d_ws, size_t ws_size,
                              hipStream_t stream) {
    const float* x = (const float*)d_in[0];
    const float* conv_w = (const float*)d_in[1];
    const float* conv_b = (const float*)d_in[2];
    const float* reg_w = (const float*)d_in[3];
    const float* reg_b = (const float*)d_in[4];
    const float* cls_w = (const float*)d_in[5];
    const float* cls_b = (const float*)d_in[6];
    float* out = (float*)d_out;
    char* ws = (char*)d_ws;

    // workspace layout (bytes) — total 160,563,200 (== r3's proven-safe size)
    // xt (6.4 MB) is ALIASED onto part[z=0]: xt is fully consumed by build_B before
    // conv_gemm runs (same-stream ordering), so the overlap is safe.
    const size_t o_part = 0;           // fp32 partials [16][784][2048] : 102,760,448
    const size_t o_xt = 0;             // fp32 [784][2048] (aliased, dead before conv)
    const size_t o_Bhi = 102760448;    // bf16 [784][18432]             : 28,901,376
    const size_t o_Blo = 131661824;    // bf16 [784][18432]             : 28,901,376

    transpose_x<<<dim3(32, 13), 256, 0, stream>>>(x, (float*)(ws + o_xt));
    build_B<<<784, 256, 0, stream>>>((const float*)(ws + o_xt), (unsigned*)(ws + o_Bhi),
                                     (unsigned*)(ws + o_Blo));
    conv_gemm<<<dim3(16, 7, 16), 256, 0, stream>>>(conv_w, ws, (uint32_t)o_Bhi,
                                                   (uint32_t)o_Blo, (float*)(ws + o_part));
    heads<<<784, 256, 0, stream>>>((const float*)(ws + o_part), conv_b, reg_w, reg_b,
                                   cls_w, cls_b, out);
}

// Round 2
// 505.263 us; speedup vs baseline: 1.0370x; 1.0370x over previous
//
#include <hip/hip_runtime.h>
#include <cstdint>

typedef __attribute__((ext_vector_type(8))) short s8v;   // 8 x bf16 (as i16)
typedef __attribute__((ext_vector_type(4))) float f4v;   // MFMA accumulator

__device__ __forceinline__ unsigned short bf16_rne(float f) {
    unsigned u = __float_as_uint(f);
    u += 0x7FFFu + ((u >> 16) & 1u);
    return (unsigned short)(u >> 16);
}
__device__ __forceinline__ float bf16f(unsigned short h) {
    return __uint_as_float(((unsigned)h) << 16);
}
// RNE pair-split (used in build_B where VALU is not critical)
__device__ __forceinline__ void cvt2(float a, float b, unsigned& hiw, unsigned& low) {
    unsigned ua = __float_as_uint(a), ub = __float_as_uint(b);
    unsigned ha = ua + 0x7FFFu + ((ua >> 16) & 1u);
    unsigned hb = ub + 0x7FFFu + ((ub >> 16) & 1u);
    hiw = (ha >> 16) | (hb & 0xFFFF0000u);
    float ra = a - __uint_as_float(ha & 0xFFFF0000u);
    float rb = b - __uint_as_float(hb & 0xFFFF0000u);
    unsigned la = __float_as_uint(ra), lb = __float_as_uint(rb);
    la += 0x7FFFu + ((la >> 16) & 1u);
    lb += 0x7FFFu + ((lb >> 16) & 1u);
    low = (la >> 16) | (lb & 0xFFFF0000u);
}
// cheap truncation pair-split (conv inner loop): err <= 2^-16 |v|, ~10 VALU/pair
__device__ __forceinline__ void cvt2t(float a, float b, unsigned& hiw, unsigned& low) {
    unsigned ua = __float_as_uint(a), ub = __float_as_uint(b);
    hiw = (ua >> 16) | (ub & 0xFFFF0000u);
    float ra = a - __uint_as_float(ua & 0xFFFF0000u);
    float rb = b - __uint_as_float(ub & 0xFFFF0000u);
    unsigned la = __float_as_uint(ra), lb = __float_as_uint(rb);
    low = (la >> 16) | (lb & 0xFFFF0000u);
}
// 8 fp32 (2 float4, k-ascending) -> hi/lo bf16 fragments
__device__ __forceinline__ void cvt8(float4 a, float4 b, s8v& hi, s8v& lo) {
    unsigned h0, h1, h2, h3, l0, l1, l2, l3;
    cvt2t(a.x, a.y, h0, l0);
    cvt2t(a.z, a.w, h1, l1);
    cvt2t(b.x, b.y, h2, l2);
    cvt2t(b.z, b.w, h3, l3);
    uint4 uh{h0, h1, h2, h3}, ul{l0, l1, l2, l3};
    hi = *(s8v*)&uh;
    lo = *(s8v*)&ul;
}

// ---------------- transpose x [c][784] -> xt [p][c] fp32 (coalesced both sides) ----------
__global__ __launch_bounds__(256) void transpose_x(const float* __restrict__ x,
                                                   float* __restrict__ xt) {
    __shared__ float t[64][65];
    int c0 = blockIdx.x * 64, p0 = blockIdx.y * 64;
    int l = threadIdx.x & 63, g = threadIdx.x >> 6;
#pragma unroll
    for (int j = 0; j < 16; ++j) {
        int cc = j * 4 + g;
        int p = p0 + l;
        t[cc][l] = (p < 784) ? x[(size_t)(c0 + cc) * 784 + p] : 0.f;
    }
    __syncthreads();
#pragma unroll
    for (int j = 0; j < 16; ++j) {
        int pp = j * 4 + g;
        int p = p0 + pp;
        if (p < 784) xt[(size_t)p * 2048 + c0 + l] = t[l][pp];
    }
}

// ---------------- build im2col B: xt [p][c] fp32 -> Bhi/Blo [p][k=c*9+r] bf16 ------------
__global__ __launch_bounds__(256) void build_B(const float* __restrict__ xt,
                                               unsigned* __restrict__ Bhi,
                                               unsigned* __restrict__ Blo) {
    int p = blockIdx.x;
    int h = p / 28, w = p % 28;
#pragma unroll
    for (int it = 0; it < 4; ++it) {
        int cp = it * 256 + threadIdx.x;   // c-pair index 0..1023, c0 = 2*cp
        float va[18];
#pragma unroll
        for (int r = 0; r < 9; ++r) {
            int h2 = h + r / 3 - 1, w2 = w + r % 3 - 1;
            bool ok = (h2 >= 0) & (h2 < 28) & (w2 >= 0) & (w2 < 28);
            float2 v = ok ? ((const float2*)(xt + (size_t)(h2 * 28 + w2) * 2048))[cp]
                          : float2{0.f, 0.f};
            va[r] = v.x;
            va[9 + r] = v.y;
        }
        size_t base = (size_t)p * 9216 + (size_t)cp * 9;  // dword index
#pragma unroll
        for (int d = 0; d < 9; ++d) {
            unsigned hw, lw;
            cvt2(va[2 * d], va[2 * d + 1], hw, lw);
            Bhi[base + d] = hw;
            Blo[base + d] = lw;
        }
    }
}

// ---------------- conv implicit GEMM over k=c*9+r; z=16 K-split; trunc split -------------
// R2 schedule: A never touches LDS — each lane loads its MFMA A-fragment (8 contiguous
// fp32 of a conv_w row: row = lane&15 within the wave's 16-row tile, k-group = lane>>4)
// directly global->reg and converts in-register. This deletes all A ds_write/ds_read
// traffic (~30% of the CU LDS pipe). The freed LDS double-buffers B (2 x 14336 B =
// 28672 B < r0's 30720 B), giving ONE barrier per K-step at r0's 4-blocks/CU occupancy:
// the vmcnt(0) drain at the barrier lands AFTER the MFMA cluster, so the B-DMA for
// step t+1 is hidden under step t's compute. A(t+1) conversion sits in the pre-barrier
// slot (hidden under the drain). Numerically identical to the r0 kernel.
#define KCH 1152          // 16 * 1152 = 18432
#define NSTEP 36          // KCH / 32
#define LDS_BYTES 28672   // B dbuf: 2 x (7168 hi + 7168 lo)

__global__ __launch_bounds__(256, 4) void conv_gemm(const float* __restrict__ cw,
                                                    const char* __restrict__ wsb,
                                                    uint32_t offBhi, uint32_t offBlo,
                                                    float* __restrict__ part) {
    __shared__ char smem[LDS_BYTES];
    int tid = threadIdx.x;
    int lane = tid & 63, wave = tid >> 6;
    int bm0 = blockIdx.x * 128, bn0 = blockIdx.y * 112, z = blockIdx.z;

    // B staging: 14 real glds descriptors (7 hi + 7 lo tiles) + 2 benign dups.
    uint32_t doff[4], dldsB[4];   // dldsB relative to one B buffer (0..14335), wave-uniform
#pragma unroll
    for (int j = 0; j < 4; ++j) {
        int i = j * 4 + wave;           // 0..15
        if (i >= 14) i -= 2;            // dup (same src+dst: benign)
        bool hiP = i < 7;
        int jj = hiP ? i : i - 7;
        int prow = jj * 16 + (lane >> 2);
        int pos = lane & 3;
        int gblk = pos ^ ((prow >> 1) & 3);            // XOR swizzle @16B blocks
        uint32_t elem = (uint32_t)(bn0 + prow) * 18432 + (uint32_t)z * KCH + gblk * 8;
        doff[j] = (hiP ? offBhi : offBlo) + elem * 2;
        dldsB[j] = (hiP ? 0u : 7168u) + (uint32_t)jj * 1024;
    }

    int m = lane & 15, qd = lane >> 4;
    int sw = (m >> 1) & 3;
    uint32_t bpos = (uint32_t)m * 64 + (uint32_t)((qd ^ sw) * 16);

    // A fragment sources: lane supplies rows (wave*32+m) and (+16), k = qd*8 .. +8
    const float4* ap0 = (const float4*)(cw + (size_t)(bm0 + wave * 32 + m) * 18432
                                        + (size_t)z * KCH + (size_t)qd * 8);
    const float4* ap1 = (const float4*)(cw + (size_t)(bm0 + wave * 32 + 16 + m) * 18432
                                        + (size_t)z * KCH + (size_t)qd * 8);

    f4v acc[2][7];
#pragma unroll
    for (int a = 0; a < 2; ++a)
#pragma unroll
        for (int b = 0; b < 7; ++b) acc[a][b] = f4v{0.f, 0.f, 0.f, 0.f};

    // ---- prologue: DMA B(0) -> buf0; A(0) -> fragments ----
#pragma unroll
    for (int j = 0; j < 4; ++j) {
        __builtin_amdgcn_global_load_lds(
            (const __attribute__((address_space(1))) void*)(wsb + doff[j]),
            (__attribute__((address_space(3))) void*)(smem + dldsB[j]), 16, 0, 0);
        doff[j] += 64;  // 32 k * 2B
    }
    s8v ah[2], al[2], ahn[2], aln[2];
    {
        float4 a0 = ap0[0], a1 = ap0[1], a2 = ap1[0], a3 = ap1[1];
        ap0 += 8;
        ap1 += 8;
        cvt8(a0, a1, ah[0], al[0]);
        cvt8(a2, a3, ah[1], al[1]);
    }
    __syncthreads();   // drains DMA(0)

    // ---- main loop: ONE barrier per step ----
#pragma unroll 2
    for (int step = 0; step < NSTEP; ++step) {
        char* smB = smem + (step & 1) * 14336;
        float4 a0, a1, a2, a3;
        if (step < NSTEP - 1) {
            // issue B-DMA(step+1) into the other buffer; drains only at the barrier
            char* smBn = smem + ((step & 1) ^ 1) * 14336;
#pragma unroll
            for (int j = 0; j < 4; ++j) {
                __builtin_amdgcn_global_load_lds(
                    (const __attribute__((address_space(1))) void*)(wsb + doff[j]),
                    (__attribute__((address_space(3))) void*)(smBn + dldsB[j]), 16, 0, 0);
                doff[j] += 64;
            }
            // issue A(step+1) fragment loads (consumed after the MFMA cluster)
            a0 = ap0[0];
            a1 = ap0[1];
            a2 = ap1[0];
            a3 = ap1[1];
            ap0 += 8;
            ap1 += 8;
        }

        __builtin_amdgcn_s_setprio(1);
#pragma unroll
        for (int nt = 0; nt < 7; ++nt) {
            s8v bh = *(const s8v*)(smB + bpos + nt * 1024);
            s8v bl = *(const s8v*)(smB + 7168 + bpos + nt * 1024);
#pragma unroll
            for (int mt = 0; mt < 2; ++mt) {
                acc[mt][nt] = __builtin_amdgcn_mfma_f32_16x16x32_bf16(ah[mt], bh, acc[mt][nt], 0, 0, 0);
                acc[mt][nt] = __builtin_amdgcn_mfma_f32_16x16x32_bf16(ah[mt], bl, acc[mt][nt], 0, 0, 0);
                acc[mt][nt] = __builtin_amdgcn_mfma_f32_16x16x32_bf16(al[mt], bh, acc[mt][nt], 0, 0, 0);
            }
        }
        __builtin_amdgcn_s_setprio(0);

        if (step < NSTEP - 1) {
            // convert A(step+1) in the pre-barrier slot (hidden under DMA drain)
            cvt8(a0, a1, ahn[0], aln[0]);
            cvt8(a2, a3, ahn[1], aln[1]);
        }
        __syncthreads();   // drains this step's DMA; buffer flip
        ah[0] = ahn[0];
        ah[1] = ahn[1];
        al[0] = aln[0];
        al[1] = aln[1];
    }

    // epilogue: C row(o) = qd*4+reg, col(p) = m; one 16B store per tile
    float* pz = part + (size_t)z * 1605632;  // 784*2048
#pragma unroll
    for (int mt = 0; mt < 2; ++mt) {
        int o = bm0 + wave * 32 + mt * 16 + qd * 4;
#pragma unroll
        for (int nt = 0; nt < 7; ++nt) {
            int p = bn0 + nt * 16 + m;
            *(float4*)(pz + (size_t)p * 2048 + o) =
                float4{acc[mt][nt].x, acc[mt][nt].y, acc[mt][nt].z, acc[mt][nt].w};
        }
    }
}

// ---------------- heads: block per pixel; 16-partial reduce, 45 dots, sigmoid, scatter ---
__constant__ int HMIN_d[9] = {3, 2, 1, 6, 4, 3, 11, 8, 6};
__constant__ int WMIN_d[9] = {1, 2, 3, 3, 4, 6, 6, 8, 11};

__global__ __launch_bounds__(256) void heads(const float* __restrict__ part,
                                             const float* __restrict__ conv_b,
                                             const float* __restrict__ reg_w,
                                             const float* __restrict__ reg_b,
                                             const float* __restrict__ cls_w,
                                             const float* __restrict__ cls_b,
                                             float* __restrict__ out) {
    int tid = threadIdx.x;
    int lane = tid & 63, wave = tid >> 6;
    int p = blockIdx.x;                 // source pixel p'
    int ci = tid * 2;                   // float4-pair index: channels [tid*8, tid*8+8)

    float4 h0 = ((const float4*)conv_b)[ci];
    float4 h1 = ((const float4*)conv_b)[ci + 1];
#pragma unroll
    for (int z = 0; z < 16; ++z) {
        const float4* pz = (const float4*)(part + (size_t)z * 1605632 + (size_t)p * 2048);
        float4 a = pz[ci], b = pz[ci + 1];
        h0.x += a.x; h0.y += a.y; h0.z += a.z; h0.w += a.w;
        h1.x += b.x; h1.y += b.y; h1.z += b.z; h1.w += b.w;
    }
    h0.x = fmaxf(h0.x, 0.f); h0.y = fmaxf(h0.y, 0.f);
    h0.z = fmaxf(h0.z, 0.f); h0.w = fmaxf(h0.w, 0.f);
    h1.x = fmaxf(h1.x, 0.f); h1.y = fmaxf(h1.y, 0.f);
    h1.z = fmaxf(h1.z, 0.f); h1.w = fmaxf(h1.w, 0.f);

    float s[45];
#pragma unroll
    for (int o = 0; o < 36; ++o) {
        float4 wa = ((const float4*)(reg_w + (size_t)o * 2048))[ci];
        float4 wb = ((const float4*)(reg_w + (size_t)o * 2048))[ci + 1];
        s[o] = h0.x * wa.x + h0.y * wa.y + h0.z * wa.z + h0.w * wa.w +
               h1.x * wb.x + h1.y * wb.y + h1.z * wb.z + h1.w * wb.w;
    }
#pragma unroll
    for (int a = 0; a < 9; ++a) {
        float4 wa = ((const float4*)(cls_w + (size_t)a * 2048))[ci];
        float4 wb = ((const float4*)(cls_w + (size_t)a * 2048))[ci + 1];
        s[36 + a] = h0.x * wa.x + h0.y * wa.y + h0.z * wa.z + h0.w * wa.w +
                    h1.x * wb.x + h1.y * wb.y + h1.z * wb.z + h1.w * wb.w;
    }

    __shared__ float wsum[4][45];
    __shared__ float fin[45];
#pragma unroll
    for (int o = 0; o < 45; ++o) {
        float v = s[o];
#pragma unroll
        for (int d = 1; d < 64; d <<= 1) v += __shfl_xor(v, d, 64);
        if (lane == 0) wsum[wave][o] = v;
    }
    __syncthreads();
    if (tid < 45) fin[tid] = wsum[0][tid] + wsum[1][tid] + wsum[2][tid] + wsum[3][tid];
    __syncthreads();

    // Reference view-chain: valid set over n = pix*9 + a (geometry); data at row n from
    // channel a' = n//784, pixel p' = n%784. This block owns p'; n = a'*784 + p'.
    if (tid < 9) {
        int ap = tid;
        int n = ap * 784 + p;
        int pix = n / 9, a2 = n % 9;
        int hh = pix / 28, ww = pix % 28;
        if (hh >= HMIN_d[a2] && ww >= WMIN_d[a2]) {
            int row = 0;
#pragma unroll
            for (int a3 = 0; a3 < 9; ++a3) {
                int hm = HMIN_d[a3], wm = WMIN_d[a3];
                int full = hh - hm; if (full < 0) full = 0;
                row += full * (28 - wm);
                if (hh >= hm) { int prt = ww - wm; if (prt < 0) prt = 0; row += prt; }
                if (a3 < a2 && hh >= hm && ww >= wm) row += 1;
            }
            float cl = fin[36 + ap] + cls_b[ap];
            float keep = (1.f / (1.f + expf(-cl)) > 0.9f) ? 1.f : 0.f;
#pragma unroll
            for (int q = 0; q < 4; ++q) {
                float rl = fin[q * 9 + ap] + reg_b[q * 9 + ap];
                out[row * 4 + q] = keep / (1.f + expf(-rl));
            }
        }
    }
}

extern "C" void kernel_launch(void* const* d_in, const int* in_sizes, int n_in,
                              void* d_out, int out_size, void* d_ws, size_t ws_size,
                              hipStream_t stream) {
    const float* x = (const float*)d_in[0];
    const float* conv_w = (const float*)d_in[1];
    const float* conv_b = (const float*)d_in[2];
    const float* reg_w = (const float*)d_in[3];
    const float* reg_b = (const float*)d_in[4];
    const float* cls_w = (const float*)d_in[5];
    const float* cls_b = (const float*)d_in[6];
    float* out = (float*)d_out;
    char* ws = (char*)d_ws;

    // workspace layout (bytes) — total 160,563,200 (== r3's proven-safe size)
    // xt (6.4 MB) is ALIASED onto part[z=0]: xt is fully consumed by build_B before
    // conv_gemm runs (same-stream ordering), so the overlap is safe.
    const size_t o_part = 0;           // fp32 partials [16][784][2048] : 102,760,448
    const size_t o_xt = 0;             // fp32 [784][2048] (aliased, dead before conv)
    const size_t o_Bhi = 102760448;    // bf16 [784][18432]             : 28,901,376
    const size_t o_Blo = 131661824;    // bf16 [784][18432]             : 28,901,376

    transpose_x<<<dim3(32, 13), 256, 0, stream>>>(x, (float*)(ws + o_xt));
    build_B<<<784, 256, 0, stream>>>((const float*)(ws + o_xt), (unsigned*)(ws + o_Bhi),
                                     (unsigned*)(ws + o_Blo));
    conv_gemm<<<dim3(16, 7, 16), 256, 0, stream>>>(conv_w, ws, (uint32_t)o_Bhi,
                                                   (uint32_t)o_Blo, (float*)(ws + o_part));
    heads<<<784, 256, 0, stream>>>((const float*)(ws + o_part), conv_b, reg_w, reg_b,
                                   cls_w, cls_b, out);
}